// Round 3
// baseline (1742.355 us; speedup 1.0000x reference)
//
#include <hip/hip_runtime.h>

#define IN_DIM  8192
#define OUT_DIM 8192
#define TPB 256
#define COLS_PER_BLOCK (TPB * 4)              // 1024 columns per block (float4/thread)
#define ROWS_PER_BLOCK 64
#define NCHUNK (IN_DIM / ROWS_PER_BLOCK)      // 128 row-chunks

typedef float f4 __attribute__((ext_vector_type(4)));

// Phase 1: UNCHANGED from the 353.4 us baseline (measurement round).
__global__ void __launch_bounds__(TPB) ibp_partial_kernel(const float* __restrict__ l,
                                                          const float* __restrict__ u,
                                                          const float* __restrict__ W,
                                                          float* __restrict__ ws) {
    __shared__ float sc[ROWS_PER_BLOCK];
    __shared__ float sr[ROWS_PER_BLOCK];

    const int t    = threadIdx.x;
    const int col0 = blockIdx.x * COLS_PER_BLOCK + t * 4;
    const int row0 = blockIdx.y * ROWS_PER_BLOCK;

    if (t < ROWS_PER_BLOCK) {
        float lv = l[row0 + t];
        float uv = u[row0 + t];
        sc[t] = 0.5f * (lv + uv);
        sr[t] = 0.5f * (uv - lv);
    }
    __syncthreads();

    float cwx = 0.f, cwy = 0.f, cwz = 0.f, cww = 0.f;   // sum c*W
    float rax = 0.f, ray = 0.f, raz = 0.f, raw = 0.f;   // sum r*|W|

    const f4* Wp = reinterpret_cast<const f4*>(
        W + (size_t)row0 * OUT_DIM + col0);

    #pragma unroll 8
    for (int i = 0; i < ROWS_PER_BLOCK; ++i) {
        f4 w = __builtin_nontemporal_load(&Wp[(size_t)i * (OUT_DIM / 4)]);
        float c = sc[i];
        float r = sr[i];
        cwx = fmaf(c, w.x, cwx);  rax = fmaf(r, fabsf(w.x), rax);
        cwy = fmaf(c, w.y, cwy);  ray = fmaf(r, fabsf(w.y), ray);
        cwz = fmaf(c, w.z, cwz);  raz = fmaf(r, fabsf(w.z), raz);
        cww = fmaf(c, w.w, cww);  raw = fmaf(r, fabsf(w.w), raw);
    }

    f4 pl = {cwx - rax, cwy - ray, cwz - raz, cww - raw};
    f4 pu = {cwx + rax, cwy + ray, cwz + raz, cww + raw};

    f4* wsl = reinterpret_cast<f4*>(
        ws + (size_t)blockIdx.y * OUT_DIM + col0);
    f4* wsu = reinterpret_cast<f4*>(
        ws + (size_t)NCHUNK * OUT_DIM + (size_t)blockIdx.y * OUT_DIM + col0);
    *wsl = pl;
    *wsu = pu;
}

// Phase 2: UNCHANGED from baseline.
__global__ void __launch_bounds__(TPB) ibp_reduce_kernel(const float* __restrict__ ws,
                                                         const float* __restrict__ bias,
                                                         float* __restrict__ out) {
    const int t = blockIdx.x * TPB + threadIdx.x;   // 0 .. 16383
    const int b = t >> 13;                          // bound index (0=l, 1=u)
    const int j = t & (OUT_DIM - 1);                // column

    const float* p = ws + (size_t)b * NCHUNK * OUT_DIM + j;
    float s = 0.f;
    #pragma unroll 8
    for (int c = 0; c < NCHUNK; ++c)
        s += p[(size_t)c * OUT_DIM];

    out[t] = s + bias[j];
}

// PHASE-1 REPLICA (measurement): full phase-1 body (LDS prep + W loads +
// FMA chain + pl/pu store) repeated PASSES times.  Per-pass dur == steady
// phase-1 cost.  NT=true replicates the real kernel's nontemporal loads;
// NT=false tests plain loads.  Writes land in a private ws region (off
// floats in) so the real result is untouched.  No __restrict__ on W/ws:
// the per-pass stores may alias W, forcing genuine reloads each pass; the
// asm memory clobber is belt-and-suspenders.  Pass counts (24 vs 8) are
// chosen so every outcome is decodable from one top-5 row + dur_us
// subtraction (round-2 verified serial additivity to within 4 us).
template <bool NT, int PASSES>
__global__ void __launch_bounds__(TPB) ibp_rep_kernel(const float* l, const float* u,
                                                      const float* W, float* ws,
                                                      size_t off) {
    __shared__ float sc[ROWS_PER_BLOCK];
    __shared__ float sr[ROWS_PER_BLOCK];

    const int t    = threadIdx.x;
    const int col0 = blockIdx.x * COLS_PER_BLOCK + t * 4;
    const int row0 = blockIdx.y * ROWS_PER_BLOCK;

    if (t < ROWS_PER_BLOCK) {
        float lv = l[row0 + t];
        float uv = u[row0 + t];
        sc[t] = 0.5f * (lv + uv);
        sr[t] = 0.5f * (uv - lv);
    }
    __syncthreads();

    const f4* Wp = reinterpret_cast<const f4*>(
        W + (size_t)row0 * OUT_DIM + col0);

    #pragma unroll 1
    for (int p = 0; p < PASSES; ++p) {
        float cwx = 0.f, cwy = 0.f, cwz = 0.f, cww = 0.f;
        float rax = 0.f, ray = 0.f, raz = 0.f, raw = 0.f;

        #pragma unroll 8
        for (int i = 0; i < ROWS_PER_BLOCK; ++i) {
            f4 w;
            if (NT) w = __builtin_nontemporal_load(&Wp[(size_t)i * (OUT_DIM / 4)]);
            else    w = Wp[(size_t)i * (OUT_DIM / 4)];
            float c = sc[i];
            float r = sr[i];
            cwx = fmaf(c, w.x, cwx);  rax = fmaf(r, fabsf(w.x), rax);
            cwy = fmaf(c, w.y, cwy);  ray = fmaf(r, fabsf(w.y), ray);
            cwz = fmaf(c, w.z, cwz);  raz = fmaf(r, fabsf(w.z), raz);
            cww = fmaf(c, w.w, cww);  raw = fmaf(r, fabsf(w.w), raw);
        }

        f4 pl = {cwx - rax, cwy - ray, cwz - raz, cww - raw};
        f4 pu = {cwx + rax, cwy + ray, cwz + raz, cww + raw};

        f4* wsl = reinterpret_cast<f4*>(
            ws + off + (size_t)blockIdx.y * OUT_DIM + col0);
        f4* wsu = reinterpret_cast<f4*>(
            ws + off + (size_t)NCHUNK * OUT_DIM + (size_t)blockIdx.y * OUT_DIM + col0);
        *wsl = pl;
        *wsu = pu;
        asm volatile("" ::: "memory");   // no cross-pass CSE/hoisting
    }
}

extern "C" void kernel_launch(void* const* d_in, const int* in_sizes, int n_in,
                              void* d_out, int out_size, void* d_ws, size_t ws_size,
                              hipStream_t stream) {
    const float* l    = (const float*)d_in[0];
    const float* u    = (const float*)d_in[1];
    const float* W    = (const float*)d_in[2];
    const float* bias = (const float*)d_in[3];
    float* out = (float*)d_out;
    float* ws  = (float*)d_ws;   // real result uses first 8 MB; replicas use +32MB/+96MB

    dim3 grid1(OUT_DIM / COLS_PER_BLOCK, NCHUNK);   // (8, 128) = 1024 blocks
    ibp_partial_kernel<<<grid1, TPB, 0, stream>>>(l, u, W, ws);

    ibp_reduce_kernel<<<(2 * OUT_DIM) / TPB, TPB, 0, stream>>>(ws, bias, out);

    // Measurement replicas (removed once P1 is pinned):
    //   A: nontemporal loads, 24 passes  -> dur 1.1ms (fast world) / 3.6ms (slow world)
    //   B: plain loads,        8 passes  -> dur 0.35ms / 1.2ms
    ibp_rep_kernel<true, 24><<<grid1, TPB, 0, stream>>>(l, u, W, ws,
                                                        (size_t)8 * 1024 * 1024);
    ibp_rep_kernel<false, 8><<<grid1, TPB, 0, stream>>>(l, u, W, ws,
                                                        (size_t)24 * 1024 * 1024);
}

// Round 5
// 375.416 us; speedup vs baseline: 4.6411x; 4.6411x over previous
//
#include <hip/hip_runtime.h>

#define IN_DIM  8192
#define OUT_DIM 8192
#define TPB 256
#define COLS_PER_BLOCK (TPB * 4)              // 1024 columns per block (float4/thread)
#define ROWS_PER_BLOCK 64
#define NCHUNK (IN_DIM / ROWS_PER_BLOCK)      // 128 row-chunks

typedef float f4 __attribute__((ext_vector_type(4)));

// Phase 1: each block reduces a 64-row x 1024-col slab of W into per-chunk
// partials (no atomics).  pl = sum c*W - r*|W|, pu = sum c*W + r*|W|,
// c=(l+u)/2, r=(u-l)/2.
// ws layout: [bound(2)][chunk(128)][col(8192)] floats = 8 MB.
//
// Loads are PLAIN (not nontemporal): round-3 A/B replicas measured the full
// phase-1 body at 40.5 us/pass with plain loads vs 44.4 us/pass with
// __builtin_nontemporal_load -- plain lets L3 retain part of W (probe:
// ~54% of the 268 MB stream served without HBM fetch), nt defeats that.
// Grid (8,128)=1024 blocks is probe-verified to saturate the ~6.33 TB/s
// achievable streaming ceiling for this exact access pattern.
__global__ void __launch_bounds__(TPB) ibp_partial_kernel(const float* __restrict__ l,
                                                          const float* __restrict__ u,
                                                          const float* __restrict__ W,
                                                          float* __restrict__ ws) {
    __shared__ float sc[ROWS_PER_BLOCK];
    __shared__ float sr[ROWS_PER_BLOCK];

    const int t    = threadIdx.x;
    const int col0 = blockIdx.x * COLS_PER_BLOCK + t * 4;
    const int row0 = blockIdx.y * ROWS_PER_BLOCK;

    if (t < ROWS_PER_BLOCK) {
        float lv = l[row0 + t];
        float uv = u[row0 + t];
        sc[t] = 0.5f * (lv + uv);
        sr[t] = 0.5f * (uv - lv);
    }
    __syncthreads();

    float cwx = 0.f, cwy = 0.f, cwz = 0.f, cww = 0.f;   // sum c*W
    float rax = 0.f, ray = 0.f, raz = 0.f, raw = 0.f;   // sum r*|W|

    const f4* Wp = reinterpret_cast<const f4*>(
        W + (size_t)row0 * OUT_DIM + col0);

    #pragma unroll 8
    for (int i = 0; i < ROWS_PER_BLOCK; ++i) {
        f4 w = Wp[(size_t)i * (OUT_DIM / 4)];
        float c = sc[i];
        float r = sr[i];
        cwx = fmaf(c, w.x, cwx);  rax = fmaf(r, fabsf(w.x), rax);
        cwy = fmaf(c, w.y, cwy);  ray = fmaf(r, fabsf(w.y), ray);
        cwz = fmaf(c, w.z, cwz);  raz = fmaf(r, fabsf(w.z), raz);
        cww = fmaf(c, w.w, cww);  raw = fmaf(r, fabsf(w.w), raw);
    }

    f4 pl = {cwx - rax, cwy - ray, cwz - raz, cww - raw};
    f4 pu = {cwx + rax, cwy + ray, cwz + raz, cww + raw};

    f4* wsl = reinterpret_cast<f4*>(
        ws + (size_t)blockIdx.y * OUT_DIM + col0);
    f4* wsu = reinterpret_cast<f4*>(
        ws + (size_t)NCHUNK * OUT_DIM + (size_t)blockIdx.y * OUT_DIM + col0);
    *wsl = pl;
    *wsu = pu;
}

// Phase 2: one thread per (bound, col): sum NCHUNK partials + bias.
// 16384 threads = 64 blocks; reads fully coalesced, mostly L2/L3 hits
// (~8 MB, written just before by phase 1).  ~5-10 us incl. launch.
__global__ void __launch_bounds__(TPB) ibp_reduce_kernel(const float* __restrict__ ws,
                                                         const float* __restrict__ bias,
                                                         float* __restrict__ out) {
    const int t = blockIdx.x * TPB + threadIdx.x;   // 0 .. 16383
    const int b = t >> 13;                          // bound index (0=l, 1=u)
    const int j = t & (OUT_DIM - 1);                // column

    const float* p = ws + (size_t)b * NCHUNK * OUT_DIM + j;
    float s = 0.f;
    #pragma unroll 8
    for (int c = 0; c < NCHUNK; ++c)
        s += p[(size_t)c * OUT_DIM];

    out[t] = s + bias[j];
}

// Session accounting (rounds 0-3, probe-verified):
//   dur_us 353.4 = harness ws-poison fill (161, 1 GiB @ 6.6 TB/s)
//                + phase 1 (~42-44: 268 MB W stream @ 6.33 TB/s achieved ceiling)
//                + phase 2 (~5-10)
//                + ~140 of fixed harness ops/gaps outside kernel_launch's control.
//   Phase-1 floor for this pattern = 42.4 us (16-pass nt probe, round 2);
//   full phase-1 body measured at 40.5 us/pass plain (24/8-pass replicas,
//   round 3).  The controllable slice is within ~10 us of its floor.
extern "C" void kernel_launch(void* const* d_in, const int* in_sizes, int n_in,
                              void* d_out, int out_size, void* d_ws, size_t ws_size,
                              hipStream_t stream) {
    const float* l    = (const float*)d_in[0];
    const float* u    = (const float*)d_in[1];
    const float* W    = (const float*)d_in[2];
    const float* bias = (const float*)d_in[3];
    float* out = (float*)d_out;
    float* ws  = (float*)d_ws;   // 2 * 128 * 8192 floats = 8 MB (ws_size >= 1 GiB)

    dim3 grid1(OUT_DIM / COLS_PER_BLOCK, NCHUNK);   // (8, 128) = 1024 blocks
    ibp_partial_kernel<<<grid1, TPB, 0, stream>>>(l, u, W, ws);

    ibp_reduce_kernel<<<(2 * OUT_DIM) / TPB, TPB, 0, stream>>>(ws, bias, out);
}

// Round 6
// 354.734 us; speedup vs baseline: 4.9117x; 1.0583x over previous
//
#include <hip/hip_runtime.h>

#define IN_DIM  8192
#define OUT_DIM 8192
#define TPB 256
#define COLS_PER_BLOCK (TPB * 4)              // 1024 columns per block (float4/thread)
#define ROWS_PER_BLOCK 64
#define NCHUNK (IN_DIM / ROWS_PER_BLOCK)      // 128 row-chunks

typedef float f4 __attribute__((ext_vector_type(4)));

// Phase 1: each block reduces a 64-row x 1024-col slab of W into per-chunk
// partials (no atomics).  pl = sum c*W - r*|W|, pu = sum c*W + r*|W|,
// c=(l+u)/2, r=(u-l)/2.
// ws layout: [bound(2)][chunk(128)][col(8192)] floats = 8 MB.
//
// W loads are NONTEMPORAL -- this is deliberate and A/B-verified BOTH ways:
//   - round-3 steady-state replicas: plain 40.5 vs nt 44.4 us/pass (plain
//     wins when W is L3-warm and the fill dirt has drained), BUT
//   - round-5 end-to-end: plain loads cost +22 us (375.4 vs 353.4).  The
//     real iteration runs cold, right after the harness's 1 GiB ws poison
//     fill: L3 is full of dirty fill lines, plain W-loads force writeback
//     evictions on the critical path, and W (read-once) gains nothing from
//     allocation.  nt skips the allocate -> skips the eviction storm.
// Do NOT switch these to plain loads based on steady-state microbenches.
__global__ void __launch_bounds__(TPB) ibp_partial_kernel(const float* __restrict__ l,
                                                          const float* __restrict__ u,
                                                          const float* __restrict__ W,
                                                          float* __restrict__ ws) {
    __shared__ float sc[ROWS_PER_BLOCK];
    __shared__ float sr[ROWS_PER_BLOCK];

    const int t    = threadIdx.x;
    const int col0 = blockIdx.x * COLS_PER_BLOCK + t * 4;
    const int row0 = blockIdx.y * ROWS_PER_BLOCK;

    if (t < ROWS_PER_BLOCK) {
        float lv = l[row0 + t];
        float uv = u[row0 + t];
        sc[t] = 0.5f * (lv + uv);
        sr[t] = 0.5f * (uv - lv);
    }
    __syncthreads();

    float cwx = 0.f, cwy = 0.f, cwz = 0.f, cww = 0.f;   // sum c*W
    float rax = 0.f, ray = 0.f, raz = 0.f, raw = 0.f;   // sum r*|W|

    const f4* Wp = reinterpret_cast<const f4*>(
        W + (size_t)row0 * OUT_DIM + col0);

    #pragma unroll 8
    for (int i = 0; i < ROWS_PER_BLOCK; ++i) {
        f4 w = __builtin_nontemporal_load(&Wp[(size_t)i * (OUT_DIM / 4)]);
        float c = sc[i];
        float r = sr[i];
        cwx = fmaf(c, w.x, cwx);  rax = fmaf(r, fabsf(w.x), rax);
        cwy = fmaf(c, w.y, cwy);  ray = fmaf(r, fabsf(w.y), ray);
        cwz = fmaf(c, w.z, cwz);  raz = fmaf(r, fabsf(w.z), raz);
        cww = fmaf(c, w.w, cww);  raw = fmaf(r, fabsf(w.w), raw);
    }

    f4 pl = {cwx - rax, cwy - ray, cwz - raz, cww - raw};
    f4 pu = {cwx + rax, cwy + ray, cwz + raz, cww + raw};

    f4* wsl = reinterpret_cast<f4*>(
        ws + (size_t)blockIdx.y * OUT_DIM + col0);
    f4* wsu = reinterpret_cast<f4*>(
        ws + (size_t)NCHUNK * OUT_DIM + (size_t)blockIdx.y * OUT_DIM + col0);
    *wsl = pl;
    *wsu = pu;
}

// Phase 2: one thread per (bound, col): sum NCHUNK partials + bias.
// 16384 threads = 64 blocks; reads fully coalesced, mostly L2/L3 hits
// (~8 MB, written just before by phase 1).  ~5-10 us incl. launch.
__global__ void __launch_bounds__(TPB) ibp_reduce_kernel(const float* __restrict__ ws,
                                                         const float* __restrict__ bias,
                                                         float* __restrict__ out) {
    const int t = blockIdx.x * TPB + threadIdx.x;   // 0 .. 16383
    const int b = t >> 13;                          // bound index (0=l, 1=u)
    const int j = t & (OUT_DIM - 1);                // column

    const float* p = ws + (size_t)b * NCHUNK * OUT_DIM + j;
    float s = 0.f;
    #pragma unroll 8
    for (int c = 0; c < NCHUNK; ++c)
        s += p[(size_t)c * OUT_DIM];

    out[t] = s + bias[j];
}

// Session accounting (rounds 0-5, probe-verified):
//   dur_us 353.4 = harness ws-poison fill (161, 1 GiB @ ~6.6 TB/s, untouchable)
//                + phase 1 (~44: 268 MB W stream; pattern floor 42.4 us, round-2 probe)
//                + phase 2 (~7)
//                + ~140 of fixed harness ops/gaps outside kernel_launch's control
//                  (invariant across two sessions and five different artifacts).
//   Cache policy A/B'd end-to-end both ways (nt 353.4 vs plain 375.4, round 5).
//   Controllable slice is within ~1% of its measured floor.
extern "C" void kernel_launch(void* const* d_in, const int* in_sizes, int n_in,
                              void* d_out, int out_size, void* d_ws, size_t ws_size,
                              hipStream_t stream) {
    const float* l    = (const float*)d_in[0];
    const float* u    = (const float*)d_in[1];
    const float* W    = (const float*)d_in[2];
    const float* bias = (const float*)d_in[3];
    float* out = (float*)d_out;
    float* ws  = (float*)d_ws;   // 2 * 128 * 8192 floats = 8 MB (ws_size >= 1 GiB)

    dim3 grid1(OUT_DIM / COLS_PER_BLOCK, NCHUNK);   // (8, 128) = 1024 blocks
    ibp_partial_kernel<<<grid1, TPB, 0, stream>>>(l, u, W, ws);

    ibp_reduce_kernel<<<(2 * OUT_DIM) / TPB, TPB, 0, stream>>>(ws, bias, out);
}